// Round 6
// baseline (252.523 us; speedup 1.0000x reference)
//
#include <hip/hip_runtime.h>
#include <math.h>

#define B 32
#define T 50
#define KK 10
#define NC 80
#define A_TOT 8400
#define EPSF 1e-7f
#define IOU_THR 0.1f

#define WORDS_PER_B 264           // ceil(8400/32)=263, padded to 264
#define BITS_BYTES (B * WORDS_PER_B * 4)
// ws layout: [0..3] ticket u32 | [4..15] pad | [16 .. 16+BITS_BYTES) dedupe bits
//            | then 1600 * 4 floats of partials (not zeroed; fully written)
#define ZERO_BYTES (16 + BITS_BYTES)

__device__ __forceinline__ float softplus_bce0(float x) {
    // BCEWithLogits(x, 0) = max(x,0) + log(1 + exp(-|x|)); fast hw exp/log.
    // exp arg <= 0 so exp in (0,1]; 1+e in (1,2] -> log well-conditioned.
    return fmaxf(x, 0.0f) + __logf(1.0f + __expf(-fabsf(x)));
}

__device__ __forceinline__ void decode_level(int a, int& aa, int& W, int& HW, float& s) {
    if (a < 6400)      { aa = a;        W = 80; HW = 6400; s = 8.0f;  }
    else if (a < 8000) { aa = a - 6400; W = 40; HW = 1600; s = 16.0f; }
    else               { aa = a - 8000; W = 20; HW = 400;  s = 32.0f; }
}

// pack (dist, idx) into one u64: non-negative IEEE floats order as unsigned,
// low 32 bits = anchor id -> u64 compare == lexicographic (dist, idx).
__device__ __forceinline__ unsigned long long pack_key(float d, int id) {
    return ((unsigned long long)__float_as_uint(d) << 32) | (unsigned int)id;
}

__device__ __forceinline__ void cswk(unsigned long long& ka, unsigned long long& kb) {
    if (kb < ka) { unsigned long long t = ka; ka = kb; kb = t; }
}

// ---------------------------------------------------------------------------
// Fully fused kernel, one wave per (b,t):
//  1. top-10 nearest anchors via clamped 8x8 windows per level, exact
//     (dist, idx) u64-key wave merge = jax.lax.top_k semantics.
//  2. decode/IoU/CIoU/assignment; obj logits of all 10 candidates preloaded
//     speculatively (removes the tail round-trip after the dedupe atomic).
//  3. cls BCE via flat-parallel gathers over (assigned anchor, class) items.
//  4. objectness dense softplus over this block's slice.
//  5. last-block-done final reduction (agent-scope release/acquire on
//     partials per CDNA4 cross-XCD coherence rules) -> writes d_out.
// ---------------------------------------------------------------------------
__global__ __launch_bounds__(64) void fused_kernel(
    const float* __restrict__ c3, const float* __restrict__ r3,
    const float* __restrict__ c4, const float* __restrict__ r4,
    const float* __restrict__ c5, const float* __restrict__ r5,
    const float* __restrict__ o3, const float* __restrict__ o4,
    const float* __restrict__ o5, const float* __restrict__ targets,
    unsigned int* __restrict__ ticket, unsigned int* __restrict__ bits,
    float* __restrict__ partials, float* __restrict__ out)
{
    int bt = blockIdx.x;              // b*T + t
    int b = bt / T;
    int lane = threadIdx.x;

    // ---- issue obj dense loads immediately (no dependencies) ----
    int gt = bt * 64 + lane;                   // 102400 threads total
    float ov0 = o3[gt];                        // B*6400 = 204800
    float ov1 = o3[gt + 102400];
    float ov2 = (gt < 51200) ? o4[gt] : 0.0f;  // B*1600
    float ov3 = (gt < 12800) ? o5[gt] : 0.0f;  // B*400

    const float* tg = targets + bt * 5;
    float tw = tg[2], th = tg[3];
    float tcx = tg[0] + tw * 0.5f, tcy = tg[1] + th * 0.5f;
    int tcls = (int)tg[4];

    // ---------------- top-k via 8x8 windows ----------------
    int ci = lane & 7, ri = lane >> 3;

    unsigned long long k0, k1, k2;
    {
        // P3: s=8, 80x80
        int j0 = (int)(tcx * 0.125f), i0 = (int)(tcy * 0.125f);
        int js = min(max(j0 - 3, 0), 72), is = min(max(i0 - 3, 0), 72);
        int j = js + ci, i = is + ri;
        float dx = j * 8.0f + 4.0f - tcx, dy = i * 8.0f + 4.0f - tcy;
        k0 = pack_key(sqrtf(dx * dx + dy * dy), i * 80 + j);
    }
    {
        // P4: s=16, 40x40
        int j0 = (int)(tcx * 0.0625f), i0 = (int)(tcy * 0.0625f);
        int js = min(max(j0 - 3, 0), 32), is = min(max(i0 - 3, 0), 32);
        int j = js + ci, i = is + ri;
        float dx = j * 16.0f + 8.0f - tcx, dy = i * 16.0f + 8.0f - tcy;
        k1 = pack_key(sqrtf(dx * dx + dy * dy), 6400 + i * 40 + j);
    }
    {
        // P5: s=32, 20x20
        int j0 = (int)(tcx * 0.03125f), i0 = (int)(tcy * 0.03125f);
        int js = min(max(j0 - 3, 0), 12), is = min(max(i0 - 3, 0), 12);
        int j = js + ci, i = is + ri;
        float dx = j * 32.0f + 16.0f - tcx, dy = i * 32.0f + 16.0f - tcy;
        k2 = pack_key(sqrtf(dx * dx + dy * dy), 8000 + i * 20 + j);
    }
    // sort the lane's 3 candidates ascending
    cswk(k0, k1); cswk(k1, k2); cswk(k0, k1);

    // merge: 10 rounds of wave-wide u64 min over lane heads;
    // lane k keeps the k-th selected anchor in `a`. Keys are unique.
    int a = 0;
    for (int k = 0; k < KK; ++k) {
        unsigned long long bk = k0;
#pragma unroll
        for (int sft = 1; sft < 64; sft <<= 1) {
            unsigned long long ok = __shfl_xor(bk, sft);
            if (ok < bk) bk = ok;
        }
        if (k0 == bk) {                  // exactly one lane (keys unique)
            k0 = k1; k1 = k2; k2 = ~0ull;
        }
        if (lane == k) a = (int)(unsigned int)(bk & 0xffffffffull);
    }

    // ---------------- assignment / CIoU ----------------
    float x21 = tcx - tw * 0.5f, y21 = tcy - th * 0.5f;
    float x22 = tcx + tw * 0.5f, y22 = tcy + th * 0.5f;

    float iou = -INFINITY, ciou = 0.0f, ospec = 0.0f;
    bool valid = false;
    if (lane < KK) {
        int aa, W, HW; float s;
        decode_level(a, aa, W, HW, s);
        int i = aa / W, j = aa - i * W;
        const float* rb = (HW == 6400) ? r3 : (HW == 1600 ? r4 : r5);
        const float* ob = (HW == 6400) ? o3 : (HW == 1600 ? o4 : o5);
        size_t rbase = ((size_t)b * 4) * (size_t)HW + (size_t)aa;
        float r0 = rb[rbase];
        float r1 = rb[rbase + (size_t)HW];
        float r2 = rb[rbase + 2 * (size_t)HW];
        float r3v = rb[rbase + 3 * (size_t)HW];
        ospec = ob[(size_t)b * HW + aa];        // speculative obj logit
        float px = ((float)j + 1.0f / (1.0f + __expf(-r0))) * s;
        float py = ((float)i + 1.0f / (1.0f + __expf(-r1))) * s;
        float pw = __expf(r2) * s;
        float ph = __expf(r3v) * s;
        float x11 = px - pw * 0.5f, y11 = py - ph * 0.5f;
        float x12 = px + pw * 0.5f, y12 = py + ph * 0.5f;
        float iw = fmaxf(fminf(x12, x22) - fmaxf(x11, x21), 0.0f);
        float ih = fmaxf(fminf(y12, y22) - fmaxf(y11, y21), 0.0f);
        float inter = iw * ih;
        float a1 = (x12 - x11) * (y12 - y11);
        float a2 = (x22 - x21) * (y22 - y21);
        float uni = a1 + a2 - inter + EPSF;
        iou = inter / uni;
        valid = iou > IOU_THR;
        float cw = fmaxf(x12, x22) - fminf(x11, x21);
        float ch = fmaxf(y12, y22) - fminf(y11, y21);
        float c2 = cw * cw + ch * ch + EPSF;
        float ddx = x21 + x22 - x11 - x12;
        float ddy = y21 + y22 - y11 - y12;
        float rho2 = (ddx * ddx + ddy * ddy) * 0.25f;
        const float CPI = (float)(4.0 / (3.14159 * 3.14159));
        float dat = atanf((x22 - x21) / (y22 - y21 + EPSF))
                  - atanf((x12 - x11) / (y12 - y11 + EPSF));
        float v = CPI * dat * dat;
        float alpha = v / (1.0f - iou + v + EPSF);
        ciou = iou - (rho2 / c2 + v * alpha);
    }

    unsigned long long vmask = __ballot(valid);
    bool has_valid = (vmask != 0ull);

    // argmax over k of iou, first occurrence (lanes>=KK carry -inf)
    float bi = iou; int bl = lane;
#pragma unroll
    for (int sft = 1; sft < 64; sft <<= 1) {
        float oi = __shfl_xor(bi, sft);
        int ol  = __shfl_xor(bl, sft);
        if (oi > bi || (oi == bi && ol < bl)) { bi = oi; bl = ol; }
    }

    bool w = (lane < KK) && (has_valid ? valid : (lane == bl));
    unsigned long long wmask0 = __ballot(w);
    int nw = __popcll(wmask0);

    // regression: sum (1 - ciou) over assigned
    float regc = w ? (1.0f - ciou) : 0.0f;
#pragma unroll
    for (int sft = 1; sft < 64; sft <<= 1) regc += __shfl_xor(regc, sft);

    // ---- objectness dedupe atomic: issue now, consume below ----
    unsigned int oldbits = 0, bit = 0;
    if (w) {
        bit = 1u << (a & 31);
        oldbits = atomicOr(&bits[b * WORDS_PER_B + (a >> 5)], bit);
    }

    // ---- compact assigned anchor ids to LDS ----
    __shared__ int s_aid[16];
    if (w) {
        int rank = __popcll(wmask0 & ((1ull << lane) - 1ull));
        s_aid[rank] = a;
    }
    __syncthreads();
    int n_items = nw * NC;

    // ---------------- classification ----------------
    // sum over (assigned anchor, class) items of softplus(x) - (c==tcls)*x.
    // Items 0..255 (covers nw<=3) gathered with 4 parallel loads per lane.
    auto cls_ptr = [&](int item, int& c) -> const float* {
        int k = item / NC;
        c = item - k * NC;
        int ak = s_aid[k];
        int aak, Wk, HWk; float sk;
        decode_level(ak, aak, Wk, HWk, sk);
        const float* cb = (HWk == 6400) ? c3 : (HWk == 1600 ? c4 : c5);
        return cb + ((size_t)b * NC + (size_t)c) * (size_t)HWk + (size_t)aak;
    };

    bool m0 = lane < n_items;
    bool m1 = 64 + lane < n_items;
    bool m2 = 128 + lane < n_items;
    bool m3 = 192 + lane < n_items;
    int cc0 = 0, cc1 = 0, cc2 = 0, cc3 = 0;
    float v0 = 0.0f, v1 = 0.0f, v2 = 0.0f, v3 = 0.0f;
    if (m0) v0 = *cls_ptr(lane, cc0);
    if (m1) v1 = *cls_ptr(64 + lane, cc1);
    if (m2) v2 = *cls_ptr(128 + lane, cc2);
    if (m3) v3 = *cls_ptr(192 + lane, cc3);

    // objectness sum while cls loads are in flight; dedupe uses the
    // speculatively preloaded logit (no new memory round trip here).
    float osum = softplus_bce0(ov0) + softplus_bce0(ov1);
    if (gt < 51200) osum += softplus_bce0(ov2);
    if (gt < 12800) osum += softplus_bce0(ov3);
    if (w && !(oldbits & bit)) osum -= ospec;  // exactly-once per (b, anchor)
#pragma unroll
    for (int sft = 1; sft < 64; sft <<= 1) osum += __shfl_xor(osum, sft);

    float csum = 0.0f;
    if (m0) csum += softplus_bce0(v0) - (cc0 == tcls ? v0 : 0.0f);
    if (m1) csum += softplus_bce0(v1) - (cc1 == tcls ? v1 : 0.0f);
    if (m2) csum += softplus_bce0(v2) - (cc2 == tcls ? v2 : 0.0f);
    if (m3) csum += softplus_bce0(v3) - (cc3 == tcls ? v3 : 0.0f);
    for (int base = 256; base < n_items; base += 64) {      // nw >= 4, rare
        int item = base + lane;
        if (item < n_items) {
            int c;
            float v = *cls_ptr(item, c);
            csum += softplus_bce0(v) - (c == tcls ? v : 0.0f);
        }
    }
#pragma unroll
    for (int sft = 1; sft < 64; sft <<= 1) csum += __shfl_xor(csum, sft);

    // ---------------- publish partial + last-block final reduce ----------
    // Agent-scope release stores + acq-rel ticket + acquire loads: the
    // CDNA4-correct cross-XCD visibility chain (per-XCD L2s not coherent).
    unsigned int t = 0;
    if (lane == 0) {
        float* pf = partials + bt * 4;
        __hip_atomic_store(pf + 0, regc, __ATOMIC_RELEASE, __HIP_MEMORY_SCOPE_AGENT);
        __hip_atomic_store(pf + 1, csum, __ATOMIC_RELEASE, __HIP_MEMORY_SCOPE_AGENT);
        __hip_atomic_store(pf + 2, (float)nw, __ATOMIC_RELEASE, __HIP_MEMORY_SCOPE_AGENT);
        __hip_atomic_store(pf + 3, osum, __ATOMIC_RELEASE, __HIP_MEMORY_SCOPE_AGENT);
        t = __hip_atomic_fetch_add(ticket, 1u, __ATOMIC_ACQ_REL, __HIP_MEMORY_SCOPE_AGENT);
    }
    t = __shfl(t, 0);
    if (t == (unsigned int)(B * T - 1)) {       // this block finished last
        float reg = 0.0f, cls = 0.0f, np = 0.0f, obj = 0.0f;
        for (int i = lane; i < B * T; i += 64) {
            const float* q = partials + i * 4;
            reg += __hip_atomic_load(q + 0, __ATOMIC_ACQUIRE, __HIP_MEMORY_SCOPE_AGENT);
            cls += __hip_atomic_load(q + 1, __ATOMIC_ACQUIRE, __HIP_MEMORY_SCOPE_AGENT);
            np  += __hip_atomic_load(q + 2, __ATOMIC_ACQUIRE, __HIP_MEMORY_SCOPE_AGENT);
            obj += __hip_atomic_load(q + 3, __ATOMIC_ACQUIRE, __HIP_MEMORY_SCOPE_AGENT);
        }
#pragma unroll
        for (int sft = 1; sft < 64; sft <<= 1) {
            reg += __shfl_xor(reg, sft);
            cls += __shfl_xor(cls, sft);
            np  += __shfl_xor(np, sft);
            obj += __shfl_xor(obj, sft);
        }
        if (lane == 0) {
            float npf = fmaxf(np, 1.0f);
            float reg_l = reg / npf, cls_l = cls / npf, obj_l = obj / npf;
            out[0] = 5.0f * reg_l + obj_l + cls_l;
            out[1] = reg_l;
            out[2] = obj_l;
            out[3] = cls_l;
        }
    }
}

extern "C" void kernel_launch(void* const* d_in, const int* in_sizes, int n_in,
                              void* d_out, int out_size, void* d_ws, size_t ws_size,
                              hipStream_t stream) {
    const float* p3c = (const float*)d_in[0];
    const float* p3r = (const float*)d_in[1];
    const float* p3o = (const float*)d_in[2];
    const float* p4c = (const float*)d_in[3];
    const float* p4r = (const float*)d_in[4];
    const float* p4o = (const float*)d_in[5];
    const float* p5c = (const float*)d_in[6];
    const float* p5r = (const float*)d_in[7];
    const float* p5o = (const float*)d_in[8];
    const float* targets = (const float*)d_in[9];

    char* ws = (char*)d_ws;
    unsigned int* ticket = (unsigned int*)ws;             // [0..3]
    unsigned int* bits = (unsigned int*)(ws + 16);        // B*264 u32
    float* partials = (float*)(ws + ZERO_BYTES);          // 1600 * 4 floats

    hipMemsetAsync(d_ws, 0, ZERO_BYTES, stream);

    fused_kernel<<<B * T, 64, 0, stream>>>(p3c, p3r, p4c, p4r, p5c, p5r,
                                           p3o, p4o, p5o, targets,
                                           ticket, bits, partials,
                                           (float*)d_out);
}

// Round 7
// 129.604 us; speedup vs baseline: 1.9484x; 1.9484x over previous
//
#include <hip/hip_runtime.h>
#include <math.h>

#define B 32
#define T 50
#define KK 10
#define NC 80
#define A_TOT 8400
#define EPSF 1e-7f
#define IOU_THR 0.1f

#define WORDS_PER_B 264           // ceil(8400/32)=263, padded to 264
#define BITS_BYTES (B * WORDS_PER_B * 4)

__device__ __forceinline__ float softplus_bce0(float x) {
    // BCEWithLogits(x, 0) = max(x,0) + log(1 + exp(-|x|)); hw v_exp/v_log.
    // exp arg <= 0 so exp in (0,1]; 1+e in (1,2] -> log well-conditioned.
    return fmaxf(x, 0.0f) + __logf(1.0f + __expf(-fabsf(x)));
}

__device__ __forceinline__ void decode_level(int a, int& aa, int& W, int& HW, float& s) {
    if (a < 6400)      { aa = a;        W = 80; HW = 6400; s = 8.0f;  }
    else if (a < 8000) { aa = a - 6400; W = 40; HW = 1600; s = 16.0f; }
    else               { aa = a - 8000; W = 20; HW = 400;  s = 32.0f; }
}

// pack (dist, idx) into one u64: non-negative IEEE floats order as unsigned,
// low 32 bits = anchor id -> u64 compare == lexicographic (dist, idx).
__device__ __forceinline__ unsigned long long pack_key(float d, int id) {
    return ((unsigned long long)__float_as_uint(d) << 32) | (unsigned int)id;
}

__device__ __forceinline__ void cswk(unsigned long long& ka, unsigned long long& kb) {
    if (kb < ka) { unsigned long long t = ka; ka = kb; kb = t; }
}

// ---------------------------------------------------------------------------
// Fused kernel, one wave per (b,t):
//  1. top-10 nearest anchors via clamped 8x8 windows per level, exact
//     (dist, idx) u64-key wave merge = jax.lax.top_k semantics.
//  2. decode/IoU/CIoU/assignment; obj logits of all 10 candidates preloaded
//     speculatively alongside the reg gathers (no tail round-trip after the
//     dedupe atomic).
//  3. cls BCE via flat-parallel gathers over (assigned anchor, class) items.
//  4. objectness dense softplus over this block's slice (loads at entry).
//  Writes one float4 partial per block; separate finalize kernel reduces
//  (cross-XCD visibility via the kernel dispatch boundary — cheap; in-kernel
//  agent-scope release/acquire measured 6x slower in round 6).
// ---------------------------------------------------------------------------
__global__ __launch_bounds__(64) void fused_kernel(
    const float* __restrict__ c3, const float* __restrict__ r3,
    const float* __restrict__ c4, const float* __restrict__ r4,
    const float* __restrict__ c5, const float* __restrict__ r5,
    const float* __restrict__ o3, const float* __restrict__ o4,
    const float* __restrict__ o5, const float* __restrict__ targets,
    unsigned int* __restrict__ bits, float4* __restrict__ partials)
{
    int bt = blockIdx.x;              // b*T + t
    int b = bt / T;
    int lane = threadIdx.x;

    // ---- issue obj dense loads immediately (no dependencies) ----
    int gt = bt * 64 + lane;                   // 102400 threads total
    float ov0 = o3[gt];                        // B*6400 = 204800
    float ov1 = o3[gt + 102400];
    float ov2 = (gt < 51200) ? o4[gt] : 0.0f;  // B*1600
    float ov3 = (gt < 12800) ? o5[gt] : 0.0f;  // B*400

    const float* tg = targets + bt * 5;
    float tw = tg[2], th = tg[3];
    float tcx = tg[0] + tw * 0.5f, tcy = tg[1] + th * 0.5f;
    int tcls = (int)tg[4];

    // ---------------- top-k via 8x8 windows ----------------
    int ci = lane & 7, ri = lane >> 3;

    unsigned long long k0, k1, k2;
    {
        // P3: s=8, 80x80
        int j0 = (int)(tcx * 0.125f), i0 = (int)(tcy * 0.125f);
        int js = min(max(j0 - 3, 0), 72), is = min(max(i0 - 3, 0), 72);
        int j = js + ci, i = is + ri;
        float dx = j * 8.0f + 4.0f - tcx, dy = i * 8.0f + 4.0f - tcy;
        k0 = pack_key(sqrtf(dx * dx + dy * dy), i * 80 + j);
    }
    {
        // P4: s=16, 40x40
        int j0 = (int)(tcx * 0.0625f), i0 = (int)(tcy * 0.0625f);
        int js = min(max(j0 - 3, 0), 32), is = min(max(i0 - 3, 0), 32);
        int j = js + ci, i = is + ri;
        float dx = j * 16.0f + 8.0f - tcx, dy = i * 16.0f + 8.0f - tcy;
        k1 = pack_key(sqrtf(dx * dx + dy * dy), 6400 + i * 40 + j);
    }
    {
        // P5: s=32, 20x20
        int j0 = (int)(tcx * 0.03125f), i0 = (int)(tcy * 0.03125f);
        int js = min(max(j0 - 3, 0), 12), is = min(max(i0 - 3, 0), 12);
        int j = js + ci, i = is + ri;
        float dx = j * 32.0f + 16.0f - tcx, dy = i * 32.0f + 16.0f - tcy;
        k2 = pack_key(sqrtf(dx * dx + dy * dy), 8000 + i * 20 + j);
    }
    // sort the lane's 3 candidates ascending
    cswk(k0, k1); cswk(k1, k2); cswk(k0, k1);

    // merge: 10 rounds of wave-wide u64 min over lane heads;
    // lane k keeps the k-th selected anchor in `a`. Keys are unique.
    int a = 0;
    for (int k = 0; k < KK; ++k) {
        unsigned long long bk = k0;
#pragma unroll
        for (int sft = 1; sft < 64; sft <<= 1) {
            unsigned long long ok = __shfl_xor(bk, sft);
            if (ok < bk) bk = ok;
        }
        if (k0 == bk) {                  // exactly one lane (keys unique)
            k0 = k1; k1 = k2; k2 = ~0ull;
        }
        if (lane == k) a = (int)(unsigned int)(bk & 0xffffffffull);
    }

    // ---------------- assignment / CIoU ----------------
    float x21 = tcx - tw * 0.5f, y21 = tcy - th * 0.5f;
    float x22 = tcx + tw * 0.5f, y22 = tcy + th * 0.5f;

    float iou = -INFINITY, ciou = 0.0f, ospec = 0.0f;
    bool valid = false;
    if (lane < KK) {
        int aa, W, HW; float s;
        decode_level(a, aa, W, HW, s);
        int i = aa / W, j = aa - i * W;
        const float* rb = (HW == 6400) ? r3 : (HW == 1600 ? r4 : r5);
        const float* ob = (HW == 6400) ? o3 : (HW == 1600 ? o4 : o5);
        size_t rbase = ((size_t)b * 4) * (size_t)HW + (size_t)aa;
        float r0 = rb[rbase];
        float r1 = rb[rbase + (size_t)HW];
        float r2 = rb[rbase + 2 * (size_t)HW];
        float r3v = rb[rbase + 3 * (size_t)HW];
        ospec = ob[(size_t)b * HW + aa];        // speculative obj logit
        float px = ((float)j + 1.0f / (1.0f + __expf(-r0))) * s;
        float py = ((float)i + 1.0f / (1.0f + __expf(-r1))) * s;
        float pw = __expf(r2) * s;
        float ph = __expf(r3v) * s;
        float x11 = px - pw * 0.5f, y11 = py - ph * 0.5f;
        float x12 = px + pw * 0.5f, y12 = py + ph * 0.5f;
        float iw = fmaxf(fminf(x12, x22) - fmaxf(x11, x21), 0.0f);
        float ih = fmaxf(fminf(y12, y22) - fmaxf(y11, y21), 0.0f);
        float inter = iw * ih;
        float a1 = (x12 - x11) * (y12 - y11);
        float a2 = (x22 - x21) * (y22 - y21);
        float uni = a1 + a2 - inter + EPSF;
        iou = inter / uni;
        valid = iou > IOU_THR;
        float cw = fmaxf(x12, x22) - fminf(x11, x21);
        float ch = fmaxf(y12, y22) - fminf(y11, y21);
        float c2 = cw * cw + ch * ch + EPSF;
        float ddx = x21 + x22 - x11 - x12;
        float ddy = y21 + y22 - y11 - y12;
        float rho2 = (ddx * ddx + ddy * ddy) * 0.25f;
        const float CPI = (float)(4.0 / (3.14159 * 3.14159));
        float dat = atanf((x22 - x21) / (y22 - y21 + EPSF))
                  - atanf((x12 - x11) / (y12 - y11 + EPSF));
        float v = CPI * dat * dat;
        float alpha = v / (1.0f - iou + v + EPSF);
        ciou = iou - (rho2 / c2 + v * alpha);
    }

    unsigned long long vmask = __ballot(valid);
    bool has_valid = (vmask != 0ull);

    // argmax over k of iou, first occurrence (lanes>=KK carry -inf)
    float bi = iou; int bl = lane;
#pragma unroll
    for (int sft = 1; sft < 64; sft <<= 1) {
        float oi = __shfl_xor(bi, sft);
        int ol  = __shfl_xor(bl, sft);
        if (oi > bi || (oi == bi && ol < bl)) { bi = oi; bl = ol; }
    }

    bool w = (lane < KK) && (has_valid ? valid : (lane == bl));
    unsigned long long wmask0 = __ballot(w);
    int nw = __popcll(wmask0);

    // regression: sum (1 - ciou) over assigned
    float regc = w ? (1.0f - ciou) : 0.0f;
#pragma unroll
    for (int sft = 1; sft < 64; sft <<= 1) regc += __shfl_xor(regc, sft);

    // ---- objectness dedupe atomic: issue now, consume below ----
    unsigned int oldbits = 0, bit = 0;
    if (w) {
        bit = 1u << (a & 31);
        oldbits = atomicOr(&bits[b * WORDS_PER_B + (a >> 5)], bit);
    }

    // ---- compact assigned anchor ids to LDS ----
    __shared__ int s_aid[16];
    if (w) {
        int rank = __popcll(wmask0 & ((1ull << lane) - 1ull));
        s_aid[rank] = a;
    }
    __syncthreads();
    int n_items = nw * NC;

    // ---------------- classification ----------------
    // sum over (assigned anchor, class) items of softplus(x) - (c==tcls)*x.
    // Items 0..255 (covers nw<=3) gathered with 4 parallel loads per lane.
    auto cls_ptr = [&](int item, int& c) -> const float* {
        int k = item / NC;
        c = item - k * NC;
        int ak = s_aid[k];
        int aak, Wk, HWk; float sk;
        decode_level(ak, aak, Wk, HWk, sk);
        const float* cb = (HWk == 6400) ? c3 : (HWk == 1600 ? c4 : c5);
        return cb + ((size_t)b * NC + (size_t)c) * (size_t)HWk + (size_t)aak;
    };

    bool m0 = lane < n_items;
    bool m1 = 64 + lane < n_items;
    bool m2 = 128 + lane < n_items;
    bool m3 = 192 + lane < n_items;
    int cc0 = 0, cc1 = 0, cc2 = 0, cc3 = 0;
    float v0 = 0.0f, v1 = 0.0f, v2 = 0.0f, v3 = 0.0f;
    if (m0) v0 = *cls_ptr(lane, cc0);
    if (m1) v1 = *cls_ptr(64 + lane, cc1);
    if (m2) v2 = *cls_ptr(128 + lane, cc2);
    if (m3) v3 = *cls_ptr(192 + lane, cc3);

    // objectness sum while cls loads are in flight; dedupe uses the
    // speculatively preloaded logit (no new memory round trip here).
    float osum = softplus_bce0(ov0) + softplus_bce0(ov1);
    if (gt < 51200) osum += softplus_bce0(ov2);
    if (gt < 12800) osum += softplus_bce0(ov3);
    if (w && !(oldbits & bit)) osum -= ospec;  // exactly-once per (b, anchor)
#pragma unroll
    for (int sft = 1; sft < 64; sft <<= 1) osum += __shfl_xor(osum, sft);

    float csum = 0.0f;
    if (m0) csum += softplus_bce0(v0) - (cc0 == tcls ? v0 : 0.0f);
    if (m1) csum += softplus_bce0(v1) - (cc1 == tcls ? v1 : 0.0f);
    if (m2) csum += softplus_bce0(v2) - (cc2 == tcls ? v2 : 0.0f);
    if (m3) csum += softplus_bce0(v3) - (cc3 == tcls ? v3 : 0.0f);
    for (int base = 256; base < n_items; base += 64) {      // nw >= 4, rare
        int item = base + lane;
        if (item < n_items) {
            int c;
            float v = *cls_ptr(item, c);
            csum += softplus_bce0(v) - (c == tcls ? v : 0.0f);
        }
    }
#pragma unroll
    for (int sft = 1; sft < 64; sft <<= 1) csum += __shfl_xor(csum, sft);

    if (lane == 0)
        partials[bt] = make_float4(regc, csum, (float)nw, osum);
}

// ---------------------------------------------------------------------------
// Finalize: reduce 1600 float4 partials -> [total, reg_l, obj_l, cls_l]
// ---------------------------------------------------------------------------
__global__ __launch_bounds__(256) void finalize_kernel(
    const float4* __restrict__ partials, float* __restrict__ out)
{
    int tid = threadIdx.x;
    float reg = 0.0f, cls = 0.0f, np = 0.0f, obj = 0.0f;
    for (int i = tid; i < B * T; i += 256) {
        float4 p = partials[i];
        reg += p.x; cls += p.y; np += p.z; obj += p.w;
    }
#pragma unroll
    for (int sft = 1; sft < 64; sft <<= 1) {
        reg += __shfl_xor(reg, sft);
        cls += __shfl_xor(cls, sft);
        np  += __shfl_xor(np, sft);
        obj += __shfl_xor(obj, sft);
    }
    __shared__ float sred[4][4];
    int wv = tid >> 6;
    if ((tid & 63) == 0) {
        sred[wv][0] = reg; sred[wv][1] = cls; sred[wv][2] = np; sred[wv][3] = obj;
    }
    __syncthreads();
    if (tid == 0) {
        float R = 0, C = 0, N = 0, O = 0;
        for (int i = 0; i < 4; ++i) {
            R += sred[i][0]; C += sred[i][1]; N += sred[i][2]; O += sred[i][3];
        }
        float npf = fmaxf(N, 1.0f);
        float reg_l = R / npf, cls_l = C / npf, obj_l = O / npf;
        out[0] = 5.0f * reg_l + obj_l + cls_l;
        out[1] = reg_l;
        out[2] = obj_l;
        out[3] = cls_l;
    }
}

extern "C" void kernel_launch(void* const* d_in, const int* in_sizes, int n_in,
                              void* d_out, int out_size, void* d_ws, size_t ws_size,
                              hipStream_t stream) {
    const float* p3c = (const float*)d_in[0];
    const float* p3r = (const float*)d_in[1];
    const float* p3o = (const float*)d_in[2];
    const float* p4c = (const float*)d_in[3];
    const float* p4r = (const float*)d_in[4];
    const float* p4o = (const float*)d_in[5];
    const float* p5c = (const float*)d_in[6];
    const float* p5r = (const float*)d_in[7];
    const float* p5o = (const float*)d_in[8];
    const float* targets = (const float*)d_in[9];

    char* ws = (char*)d_ws;
    unsigned int* bits = (unsigned int*)ws;               // B*264 u32, 33792 B
    float4* partials = (float4*)(ws + BITS_BYTES);        // 1600 float4

    hipMemsetAsync(bits, 0, BITS_BYTES, stream);

    fused_kernel<<<B * T, 64, 0, stream>>>(p3c, p3r, p4c, p4r, p5c, p5r,
                                           p3o, p4o, p5o, targets,
                                           bits, partials);
    finalize_kernel<<<1, 256, 0, stream>>>(partials, (float*)d_out);
}